// Round 1
// baseline (282.794 us; speedup 1.0000x reference)
//
#include <hip/hip_runtime.h>
#include <cstdio>

// MHA block for MI355X (gfx950). Round 0: correctness-first MFMA design.
// Pipeline: QKV proj (bf16 out, V transposed) -> flash attn -> out proj (fp32).
// ws layout (bf16): Q[S][768] | K[S][768] | Vt[768][S] | AO[S][768]  = 25.2 MB.

using u16 = unsigned short;
typedef __bf16 bf16x8 __attribute__((ext_vector_type(8)));
typedef float f32x4 __attribute__((ext_vector_type(4)));
typedef unsigned int u32x4 __attribute__((ext_vector_type(4)));
typedef u16 u16x4 __attribute__((ext_vector_type(4)));

constexpr int SEQ = 4096;
constexpr int DIM = 768;
constexpr int NH = 12;
constexpr int HD = 64;
constexpr int LDT = 72;  // padded LDS stride in bf16 elems (144B = 9*16B)

__device__ __forceinline__ u16 f2bf(float f) {
  union { float f; unsigned u; } v{f};
  unsigned r = v.u + 0x7fffu + ((v.u >> 16) & 1u);  // RNE
  return (u16)(r >> 16);
}
__device__ __forceinline__ unsigned pack2(float a, float b) {
  return (unsigned)f2bf(a) | ((unsigned)f2bf(b) << 16);
}

// out = A @ W^T + bias.  A: [4096][768] (fp32 or bf16). W: [768][768] fp32 (row = out col).
// OUT_MODE: 0 = fp32 row-major, 1 = bf16 row-major, 2 = bf16 transposed (out[n*SEQ+m])
template <bool IN_BF16, int OUT_MODE>
__global__ __launch_bounds__(256) void gemm_bias(const void* __restrict__ Ap,
                                                 const float* __restrict__ W,
                                                 const float* __restrict__ bias,
                                                 void* __restrict__ outp) {
  __shared__ alignas(16) u16 As[64 * LDT];
  __shared__ alignas(16) u16 Bs[64 * LDT];

  const int tid = threadIdx.x;
  const int lane = tid & 63;
  const int wave = tid >> 6;
  const int lg = lane >> 4;   // 16-lane group
  const int ln = lane & 15;
  const int m0 = blockIdx.y * 64;
  const int n0 = blockIdx.x * 64;
  const int sr = tid >> 2;          // staging row 0..63
  const int sc = (tid & 3) * 16;    // staging col {0,16,32,48}

  f32x4 acc[4] = {};

  for (int kk = 0; kk < DIM; kk += 64) {
    // ---- stage A tile [64][64] -> bf16 LDS ----
    if constexpr (IN_BF16) {
      const u16* Ab = (const u16*)Ap;
      const u32x4* src = (const u32x4*)(Ab + (size_t)(m0 + sr) * DIM + kk + sc);
      *(u32x4*)&As[sr * LDT + sc] = src[0];
      *(u32x4*)&As[sr * LDT + sc + 8] = src[1];
    } else {
      const float* Af = (const float*)Ap;
      const float* a = Af + (size_t)(m0 + sr) * DIM + kk + sc;
      float4 f0 = *(const float4*)(a);
      float4 f1 = *(const float4*)(a + 4);
      float4 f2 = *(const float4*)(a + 8);
      float4 f3 = *(const float4*)(a + 12);
      u32x4 w0 = {pack2(f0.x, f0.y), pack2(f0.z, f0.w), pack2(f1.x, f1.y), pack2(f1.z, f1.w)};
      u32x4 w1 = {pack2(f2.x, f2.y), pack2(f2.z, f2.w), pack2(f3.x, f3.y), pack2(f3.z, f3.w)};
      *(u32x4*)&As[sr * LDT + sc] = w0;
      *(u32x4*)&As[sr * LDT + sc + 8] = w1;
    }
    // ---- stage B tile: rows = output cols, contiguous in k ----
    {
      const float* b = W + (size_t)(n0 + sr) * DIM + kk + sc;
      float4 f0 = *(const float4*)(b);
      float4 f1 = *(const float4*)(b + 4);
      float4 f2 = *(const float4*)(b + 8);
      float4 f3 = *(const float4*)(b + 12);
      u32x4 w0 = {pack2(f0.x, f0.y), pack2(f0.z, f0.w), pack2(f1.x, f1.y), pack2(f1.z, f1.w)};
      u32x4 w1 = {pack2(f2.x, f2.y), pack2(f2.z, f2.w), pack2(f3.x, f3.y), pack2(f3.z, f3.w)};
      *(u32x4*)&Bs[sr * LDT + sc] = w0;
      *(u32x4*)&Bs[sr * LDT + sc + 8] = w1;
    }
    __syncthreads();

#pragma unroll
    for (int c = 0; c < 2; ++c) {
      const int k0 = c * 32 + lg * 8;
      bf16x8 a = __builtin_bit_cast(bf16x8, *(const u32x4*)&As[(wave * 16 + ln) * LDT + k0]);
#pragma unroll
      for (int j = 0; j < 4; ++j) {
        bf16x8 bb = __builtin_bit_cast(bf16x8, *(const u32x4*)&Bs[(j * 16 + ln) * LDT + k0]);
        acc[j] = __builtin_amdgcn_mfma_f32_16x16x32_bf16(a, bb, acc[j], 0, 0, 0);
      }
    }
    __syncthreads();
  }

  // ---- epilogue: C layout col=ln(+16j), row = wave*16 + lg*4 + r ----
  const int rowb = m0 + wave * 16 + lg * 4;
#pragma unroll
  for (int j = 0; j < 4; ++j) {
    const int col = n0 + j * 16 + ln;
    const float bv = bias[col];
    if constexpr (OUT_MODE == 0) {
      float* out = (float*)outp;
#pragma unroll
      for (int r = 0; r < 4; ++r) out[(size_t)(rowb + r) * DIM + col] = acc[j][r] + bv;
    } else if constexpr (OUT_MODE == 1) {
      u16* out = (u16*)outp;
#pragma unroll
      for (int r = 0; r < 4; ++r) out[(size_t)(rowb + r) * DIM + col] = f2bf(acc[j][r] + bv);
    } else {
      u16* out = (u16*)outp;
      u16x4 pk;
#pragma unroll
      for (int r = 0; r < 4; ++r) pk[r] = f2bf(acc[j][r] + bv);
      *(u16x4*)&out[(size_t)col * SEQ + rowb] = pk;  // transposed, 4 consecutive rows packed
    }
  }
}

// Flash attention. Grid (SEQ/64, NH), 4 waves; wave owns 16 q rows. KV tile = 64 keys.
// Q,K: [S][768] bf16.  Vt: [768][S] bf16 (per-head rows h*64..h*64+63).  AO: [S][768] bf16.
__global__ __launch_bounds__(256) void attn_kernel(const u16* __restrict__ Q,
                                                   const u16* __restrict__ K,
                                                   const u16* __restrict__ Vt,
                                                   u16* __restrict__ AO) {
  __shared__ alignas(16) u16 Ks[64 * LDT];       // [key][d]
  __shared__ alignas(16) u16 Vs[64 * LDT];       // [d][key]
  __shared__ alignas(16) u16 Ps[4 * 16 * LDT];   // per-wave P slice [16 q][64 key]

  const int tid = threadIdx.x, lane = tid & 63, wave = tid >> 6;
  const int lg = lane >> 4, ln = lane & 15;
  const int h = blockIdx.y;
  const int q0 = blockIdx.x * 64;

  // Q fragments held in registers for whole kernel (A-frag: row=ln, k = lg*8 + c*32 + j)
  bf16x8 qf[2];
  {
    const u16* qp = Q + (size_t)(q0 + wave * 16 + ln) * DIM + h * HD + lg * 8;
    qf[0] = __builtin_bit_cast(bf16x8, *(const u32x4*)qp);
    qf[1] = __builtin_bit_cast(bf16x8, *(const u32x4*)(qp + 32));
  }

  float mrun[4], lrun[4];
  f32x4 oacc[4] = {};
#pragma unroll
  for (int r = 0; r < 4; ++r) { mrun[r] = -1e30f; lrun[r] = 0.f; }

  const int sr = tid >> 2, sc = (tid & 3) * 16;

  for (int kt = 0; kt < SEQ / 64; ++kt) {
    const int key0 = kt * 64;
    {  // stage K tile [key][d]
      const u32x4* src = (const u32x4*)(K + (size_t)(key0 + sr) * DIM + h * HD + sc);
      *(u32x4*)&Ks[sr * LDT + sc] = src[0];
      *(u32x4*)&Ks[sr * LDT + sc + 8] = src[1];
    }
    {  // stage V^T tile [d][key] straight from transposed global V
      const u32x4* src = (const u32x4*)(Vt + (size_t)(h * HD + sr) * SEQ + key0 + sc);
      *(u32x4*)&Vs[sr * LDT + sc] = src[0];
      *(u32x4*)&Vs[sr * LDT + sc + 8] = src[1];
    }
    __syncthreads();

    // S = Q K^T  (B-frag from Ks: n=key=j*16+ln, k=dim contiguous)
    f32x4 sa[4];
#pragma unroll
    for (int j = 0; j < 4; ++j) {
      f32x4 s = {};
#pragma unroll
      for (int c = 0; c < 2; ++c) {
        bf16x8 kf = __builtin_bit_cast(
            bf16x8, *(const u32x4*)&Ks[(j * 16 + ln) * LDT + c * 32 + lg * 8]);
        s = __builtin_amdgcn_mfma_f32_16x16x32_bf16(qf[c], kf, s, 0, 0, 0);
      }
      sa[j] = s;
    }

    // online softmax per q-row (rows lg*4+r; key cols spread over 16 lanes of group)
    float sc_r[4];
#pragma unroll
    for (int r = 0; r < 4; ++r) {
      float v0 = sa[0][r] * 0.125f, v1 = sa[1][r] * 0.125f;
      float v2 = sa[2][r] * 0.125f, v3 = sa[3][r] * 0.125f;
      float mx = fmaxf(fmaxf(v0, v1), fmaxf(v2, v3));
#pragma unroll
      for (int msk = 1; msk < 16; msk <<= 1) mx = fmaxf(mx, __shfl_xor(mx, msk));
      const float mnew = fmaxf(mrun[r], mx);
      const float scl = __expf(mrun[r] - mnew);
      float p0 = __expf(v0 - mnew), p1 = __expf(v1 - mnew);
      float p2 = __expf(v2 - mnew), p3 = __expf(v3 - mnew);
      sa[0][r] = p0; sa[1][r] = p1; sa[2][r] = p2; sa[3][r] = p3;
      float rs = (p0 + p1) + (p2 + p3);
#pragma unroll
      for (int msk = 1; msk < 16; msk <<= 1) rs += __shfl_xor(rs, msk);
      lrun[r] = lrun[r] * scl + rs;
      mrun[r] = mnew;
      sc_r[r] = scl;
    }
#pragma unroll
    for (int nd = 0; nd < 4; ++nd)
#pragma unroll
      for (int r = 0; r < 4; ++r) oacc[nd][r] *= sc_r[r];

    // P -> bf16 LDS (per-wave private slice; within-wave ordering, no barrier needed)
#pragma unroll
    for (int j = 0; j < 4; ++j)
#pragma unroll
      for (int r = 0; r < 4; ++r)
        Ps[(wave * 16 + lg * 4 + r) * LDT + j * 16 + ln] = f2bf(sa[j][r]);

    bf16x8 pf[2];
#pragma unroll
    for (int c = 0; c < 2; ++c)
      pf[c] = __builtin_bit_cast(
          bf16x8, *(const u32x4*)&Ps[(wave * 16 + ln) * LDT + c * 32 + lg * 8]);

    // O += P V   (B-frag from Vs: n=d=nd*16+ln, k=key contiguous)
#pragma unroll
    for (int nd = 0; nd < 4; ++nd) {
#pragma unroll
      for (int c = 0; c < 2; ++c) {
        bf16x8 vf = __builtin_bit_cast(
            bf16x8, *(const u32x4*)&Vs[(nd * 16 + ln) * LDT + c * 32 + lg * 8]);
        oacc[nd] = __builtin_amdgcn_mfma_f32_16x16x32_bf16(pf[c], vf, oacc[nd], 0, 0, 0);
      }
    }
    __syncthreads();  // before next tile overwrites Ks/Vs
  }

  // epilogue: normalize and store bf16 attention output [S][768]
#pragma unroll
  for (int r = 0; r < 4; ++r) {
    const float inv = 1.f / lrun[r];
    const int row = q0 + wave * 16 + lg * 4 + r;
#pragma unroll
    for (int nd = 0; nd < 4; ++nd)
      AO[(size_t)row * DIM + h * HD + nd * 16 + ln] = f2bf(oacc[nd][r] * inv);
  }
}

extern "C" void kernel_launch(void* const* d_in, const int* in_sizes, int n_in,
                              void* d_out, int out_size, void* d_ws, size_t ws_size,
                              hipStream_t stream) {
  const float* x = (const float*)d_in[0];
  const float* wq = (const float*)d_in[1];
  const float* bq = (const float*)d_in[2];
  const float* wk = (const float*)d_in[3];
  const float* bk = (const float*)d_in[4];
  const float* wv = (const float*)d_in[5];
  const float* bv = (const float*)d_in[6];
  const float* ww = (const float*)d_in[7];
  const float* bw = (const float*)d_in[8];

  const size_t mat = (size_t)SEQ * DIM;  // bf16 elems per matrix
  if (ws_size < 4 * mat * sizeof(u16)) {
    fprintf(stderr, "kernel_launch: ws too small (%zu < %zu)\n", ws_size,
            4 * mat * sizeof(u16));
    return;
  }
  u16* Qb = (u16*)d_ws;
  u16* Kb = Qb + mat;
  u16* Vtb = Kb + mat;   // transposed: [768][4096]
  u16* AOb = Vtb + mat;

  dim3 gg(DIM / 64, SEQ / 64), bb(256);
  gemm_bias<false, 1><<<gg, bb, 0, stream>>>(x, wq, bq, Qb);
  gemm_bias<false, 1><<<gg, bb, 0, stream>>>(x, wk, bk, Kb);
  gemm_bias<false, 2><<<gg, bb, 0, stream>>>(x, wv, bv, Vtb);
  attn_kernel<<<dim3(SEQ / 64, NH), bb, 0, stream>>>(Qb, Kb, Vtb, AOb);
  gemm_bias<true, 0><<<gg, bb, 0, stream>>>(AOb, ww, bw, (float*)d_out);
}

// Round 2
// 209.535 us; speedup vs baseline: 1.3496x; 1.3496x over previous
//
#include <hip/hip_runtime.h>
#include <cstdio>

// MHA block for MI355X (gfx950). Round 1: swapped-QK in-register softmax,
// exp2 + prescaled Q, defer-max (T13), cvt_pk P-pack, async-STAGE (T14).
// Pipeline: QKV proj (bf16 out, V transposed) -> flash attn -> out proj (fp32).
// ws layout (bf16): Q[S][768] | K[S][768] | Vt[768][S] | AO[S][768]  = 25.2 MB.

using u16 = unsigned short;
typedef __bf16 bf16x8 __attribute__((ext_vector_type(8)));
typedef float f32x4 __attribute__((ext_vector_type(4)));
typedef unsigned int u32x4 __attribute__((ext_vector_type(4)));
typedef unsigned int u32x2 __attribute__((ext_vector_type(2)));
typedef u16 u16x4 __attribute__((ext_vector_type(4)));

constexpr int SEQ = 4096;
constexpr int DIM = 768;
constexpr int NH = 12;
constexpr int HD = 64;
constexpr int LDT = 72;  // padded LDS stride in bf16 elems (144B = 9*16B)
// Softmax pre-scale folded into Q projection: (1/sqrt(64)) * log2(e)
constexpr float SM_PRE = 0.18033688011112042f;
constexpr float DEFER_THR = 8.0f;  // exp2-domain defer-max threshold (T13)

__device__ __forceinline__ u16 f2bf(float f) {
  union { float f; unsigned u; } v{f};
  unsigned r = v.u + 0x7fffu + ((v.u >> 16) & 1u);  // RNE
  return (u16)(r >> 16);
}
__device__ __forceinline__ unsigned pack2(float a, float b) {
  return (unsigned)f2bf(a) | ((unsigned)f2bf(b) << 16);
}
__device__ __forceinline__ unsigned cvtpk_bf16(float a, float b) {
  unsigned r;
  asm("v_cvt_pk_bf16_f32 %0, %1, %2" : "=v"(r) : "v"(a), "v"(b));
  return r;  // lo16 = bf16(a), hi16 = bf16(b)
}

// out = scale*(A @ W^T + bias).  A: [4096][768] fp32 or bf16. W: [768][768] fp32.
// OUT_MODE: 0 = fp32 row-major, 1 = bf16 row-major, 2 = bf16 transposed
template <bool IN_BF16, int OUT_MODE>
__global__ __launch_bounds__(256) void gemm_bias(const void* __restrict__ Ap,
                                                 const float* __restrict__ W,
                                                 const float* __restrict__ bias,
                                                 void* __restrict__ outp,
                                                 float scale) {
  __shared__ alignas(16) u16 As[64 * LDT];
  __shared__ alignas(16) u16 Bs[64 * LDT];

  const int tid = threadIdx.x;
  const int lane = tid & 63;
  const int wave = tid >> 6;
  const int lg = lane >> 4;
  const int ln = lane & 15;
  const int m0 = blockIdx.y * 64;
  const int n0 = blockIdx.x * 64;
  const int sr = tid >> 2;
  const int sc = (tid & 3) * 16;

  f32x4 acc[4] = {};

  for (int kk = 0; kk < DIM; kk += 64) {
    if constexpr (IN_BF16) {
      const u16* Ab = (const u16*)Ap;
      const u32x4* src = (const u32x4*)(Ab + (size_t)(m0 + sr) * DIM + kk + sc);
      *(u32x4*)&As[sr * LDT + sc] = src[0];
      *(u32x4*)&As[sr * LDT + sc + 8] = src[1];
    } else {
      const float* Af = (const float*)Ap;
      const float* a = Af + (size_t)(m0 + sr) * DIM + kk + sc;
      float4 f0 = *(const float4*)(a);
      float4 f1 = *(const float4*)(a + 4);
      float4 f2 = *(const float4*)(a + 8);
      float4 f3 = *(const float4*)(a + 12);
      u32x4 w0 = {pack2(f0.x, f0.y), pack2(f0.z, f0.w), pack2(f1.x, f1.y), pack2(f1.z, f1.w)};
      u32x4 w1 = {pack2(f2.x, f2.y), pack2(f2.z, f2.w), pack2(f3.x, f3.y), pack2(f3.z, f3.w)};
      *(u32x4*)&As[sr * LDT + sc] = w0;
      *(u32x4*)&As[sr * LDT + sc + 8] = w1;
    }
    {
      const float* b = W + (size_t)(n0 + sr) * DIM + kk + sc;
      float4 f0 = *(const float4*)(b);
      float4 f1 = *(const float4*)(b + 4);
      float4 f2 = *(const float4*)(b + 8);
      float4 f3 = *(const float4*)(b + 12);
      u32x4 w0 = {pack2(f0.x, f0.y), pack2(f0.z, f0.w), pack2(f1.x, f1.y), pack2(f1.z, f1.w)};
      u32x4 w1 = {pack2(f2.x, f2.y), pack2(f2.z, f2.w), pack2(f3.x, f3.y), pack2(f3.z, f3.w)};
      *(u32x4*)&Bs[sr * LDT + sc] = w0;
      *(u32x4*)&Bs[sr * LDT + sc + 8] = w1;
    }
    __syncthreads();

#pragma unroll
    for (int c = 0; c < 2; ++c) {
      const int k0 = c * 32 + lg * 8;
      bf16x8 a = __builtin_bit_cast(bf16x8, *(const u32x4*)&As[(wave * 16 + ln) * LDT + k0]);
#pragma unroll
      for (int j = 0; j < 4; ++j) {
        bf16x8 bb = __builtin_bit_cast(bf16x8, *(const u32x4*)&Bs[(j * 16 + ln) * LDT + k0]);
        acc[j] = __builtin_amdgcn_mfma_f32_16x16x32_bf16(a, bb, acc[j], 0, 0, 0);
      }
    }
    __syncthreads();
  }

  const int rowb = m0 + wave * 16 + lg * 4;
#pragma unroll
  for (int j = 0; j < 4; ++j) {
    const int col = n0 + j * 16 + ln;
    const float bv = bias[col];
    if constexpr (OUT_MODE == 0) {
      float* out = (float*)outp;
#pragma unroll
      for (int r = 0; r < 4; ++r) out[(size_t)(rowb + r) * DIM + col] = acc[j][r] + bv;
    } else if constexpr (OUT_MODE == 1) {
      u16* out = (u16*)outp;
#pragma unroll
      for (int r = 0; r < 4; ++r)
        out[(size_t)(rowb + r) * DIM + col] = f2bf((acc[j][r] + bv) * scale);
    } else {
      u16* out = (u16*)outp;
      u16x4 pk;
#pragma unroll
      for (int r = 0; r < 4; ++r) pk[r] = f2bf(acc[j][r] + bv);
      *(u16x4*)&out[(size_t)col * SEQ + rowb] = pk;
    }
  }
}

// Flash attention, swapped-QK layout. Grid (SEQ/64, NH), 4 waves of 16 q-rows.
// Q prescaled by SM_PRE so scores are direct exp2 arguments.
// Q,K: [S][768] bf16.  Vt: [768][S] bf16.  AO: [S][768] bf16.
__global__ __launch_bounds__(256) void attn_kernel(const u16* __restrict__ Q,
                                                   const u16* __restrict__ K,
                                                   const u16* __restrict__ Vt,
                                                   u16* __restrict__ AO) {
  __shared__ alignas(16) u16 Ks[64 * LDT];      // [key][d]
  __shared__ alignas(16) u16 Vs[64 * LDT];      // [d][key]
  __shared__ alignas(16) u16 Ps[4 * 16 * LDT];  // per-wave P slice [q][key]

  const int tid = threadIdx.x, lane = tid & 63, wave = tid >> 6;
  const int lg = lane >> 4, ln = lane & 15;
  const int h = blockIdx.y;
  const int q0 = blockIdx.x * 64;

  // Q fragments (B-frag for swapped QK^T): n=q=ln, k=d contiguous at lg*8
  bf16x8 qf[2];
  {
    const u16* qp = Q + (size_t)(q0 + wave * 16 + ln) * DIM + h * HD + lg * 8;
    qf[0] = __builtin_bit_cast(bf16x8, *(const u32x4*)qp);
    qf[1] = __builtin_bit_cast(bf16x8, *(const u32x4*)(qp + 32));
  }

  // per-lane running stats for q = wavebase + ln (replicated across lg groups)
  float mrun = -1e30f, lrun = 0.f;
  f32x4 oacc[4] = {};  // O[q=lg*4+r][d=nd*16+ln]

  const int sr = tid >> 2, sc = (tid & 3) * 16;
  constexpr int NT = SEQ / 64;

  // prefetch tile 0 into regs (T14 async-STAGE)
  u32x4 ka, kb, va, vb;
  {
    const u32x4* ks = (const u32x4*)(K + (size_t)(0 + sr) * DIM + h * HD + sc);
    ka = ks[0]; kb = ks[1];
    const u32x4* vs = (const u32x4*)(Vt + (size_t)(h * HD + sr) * SEQ + 0 + sc);
    va = vs[0]; vb = vs[1];
  }

  for (int kt = 0; kt < NT; ++kt) {
    __syncthreads();  // all waves done reading previous tile
    *(u32x4*)&Ks[sr * LDT + sc] = ka;
    *(u32x4*)&Ks[sr * LDT + sc + 8] = kb;
    *(u32x4*)&Vs[sr * LDT + sc] = va;
    *(u32x4*)&Vs[sr * LDT + sc + 8] = vb;
    __syncthreads();

    // issue next tile's global loads now; they complete under compute
    {
      const int ktn = (kt + 1 < NT) ? kt + 1 : kt;
      const u32x4* ks = (const u32x4*)(K + (size_t)(ktn * 64 + sr) * DIM + h * HD + sc);
      ka = ks[0]; kb = ks[1];
      const u32x4* vs = (const u32x4*)(Vt + (size_t)(h * HD + sr) * SEQ + ktn * 64 + sc);
      va = vs[0]; vb = vs[1];
    }

    // S^T = K Q^T : out col=ln -> q, row=lg*4+r -> key = jt*16+lg*4+r
    f32x4 st[4];
#pragma unroll
    for (int jt = 0; jt < 4; ++jt) {
      f32x4 s = {};
#pragma unroll
      for (int c = 0; c < 2; ++c) {
        bf16x8 kf = __builtin_bit_cast(
            bf16x8, *(const u32x4*)&Ks[(jt * 16 + ln) * LDT + c * 32 + lg * 8]);
        s = __builtin_amdgcn_mfma_f32_16x16x32_bf16(kf, qf[c], s, 0, 0, 0);
      }
      st[jt] = s;
    }

    // tile max for this lane's q (16 values in-lane, then 2 shfls over lg)
    float a0 = fmaxf(fmaxf(st[0][0], st[0][1]), fmaxf(st[0][2], st[0][3]));
    float a1 = fmaxf(fmaxf(st[1][0], st[1][1]), fmaxf(st[1][2], st[1][3]));
    float a2 = fmaxf(fmaxf(st[2][0], st[2][1]), fmaxf(st[2][2], st[2][3]));
    float a3 = fmaxf(fmaxf(st[3][0], st[3][1]), fmaxf(st[3][2], st[3][3]));
    float pmax = fmaxf(fmaxf(a0, a1), fmaxf(a2, a3));
    pmax = fmaxf(pmax, __shfl_xor(pmax, 16));
    pmax = fmaxf(pmax, __shfl_xor(pmax, 32));

    // defer-max (T13): only rescale when some row's max grew past THR
    if (__ballot(pmax > mrun + DEFER_THR)) {
      const float mnew = fmaxf(mrun, pmax);
      const float scl = __builtin_amdgcn_exp2f(mrun - mnew);
      lrun *= scl;
      mrun = mnew;
      float sq[4];
#pragma unroll
      for (int r = 0; r < 4; ++r) sq[r] = __shfl(scl, lg * 4 + r);
#pragma unroll
      for (int nd = 0; nd < 4; ++nd)
#pragma unroll
        for (int r = 0; r < 4; ++r) oacc[nd][r] *= sq[r];
    }

    // P = exp2(s - m), row-sum
    f32x4 ps = {};
#pragma unroll
    for (int jt = 0; jt < 4; ++jt) {
#pragma unroll
      for (int r = 0; r < 4; ++r) {
        float p = __builtin_amdgcn_exp2f(st[jt][r] - mrun);
        st[jt][r] = p;
        ps[r] += p;
      }
    }
    float rs = (ps[0] + ps[1]) + (ps[2] + ps[3]);
    rs += __shfl_xor(rs, 16);
    rs += __shfl_xor(rs, 32);
    lrun += rs;

    // pack P -> bf16, write per-wave LDS slice [q=ln][key] (within-wave, no barrier)
#pragma unroll
    for (int jt = 0; jt < 4; ++jt) {
      u32x2 w;
      w[0] = cvtpk_bf16(st[jt][0], st[jt][1]);
      w[1] = cvtpk_bf16(st[jt][2], st[jt][3]);
      *(u32x2*)&Ps[(wave * 16 + ln) * LDT + jt * 16 + lg * 4] = w;
    }
    bf16x8 pf[2];
#pragma unroll
    for (int c = 0; c < 2; ++c)
      pf[c] = __builtin_bit_cast(
          bf16x8, *(const u32x4*)&Ps[(wave * 16 + ln) * LDT + c * 32 + lg * 8]);

    // O += P V : A=P (m=q), B from Vs (n=d, k=key contiguous)
#pragma unroll
    for (int nd = 0; nd < 4; ++nd) {
#pragma unroll
      for (int c = 0; c < 2; ++c) {
        bf16x8 vf = __builtin_bit_cast(
            bf16x8, *(const u32x4*)&Vs[(nd * 16 + ln) * LDT + c * 32 + lg * 8]);
        oacc[nd] = __builtin_amdgcn_mfma_f32_16x16x32_bf16(pf[c], vf, oacc[nd], 0, 0, 0);
      }
    }
  }

  // epilogue: normalize rows q=lg*4+r (lrun lives at lane ln==row)
#pragma unroll
  for (int r = 0; r < 4; ++r) {
    const float inv = 1.f / __shfl(lrun, lg * 4 + r);
    const int row = q0 + wave * 16 + lg * 4 + r;
#pragma unroll
    for (int nd = 0; nd < 4; ++nd)
      AO[(size_t)row * DIM + h * HD + nd * 16 + ln] = f2bf(oacc[nd][r] * inv);
  }
}

extern "C" void kernel_launch(void* const* d_in, const int* in_sizes, int n_in,
                              void* d_out, int out_size, void* d_ws, size_t ws_size,
                              hipStream_t stream) {
  const float* x = (const float*)d_in[0];
  const float* wq = (const float*)d_in[1];
  const float* bq = (const float*)d_in[2];
  const float* wk = (const float*)d_in[3];
  const float* bk = (const float*)d_in[4];
  const float* wv = (const float*)d_in[5];
  const float* bv = (const float*)d_in[6];
  const float* ww = (const float*)d_in[7];
  const float* bw = (const float*)d_in[8];

  const size_t mat = (size_t)SEQ * DIM;
  if (ws_size < 4 * mat * sizeof(u16)) {
    fprintf(stderr, "kernel_launch: ws too small (%zu)\n", ws_size);
    return;
  }
  u16* Qb = (u16*)d_ws;
  u16* Kb = Qb + mat;
  u16* Vtb = Kb + mat;  // [768][4096]
  u16* AOb = Vtb + mat;

  dim3 gg(DIM / 64, SEQ / 64), bb(256);
  gemm_bias<false, 1><<<gg, bb, 0, stream>>>(x, wq, bq, Qb, SM_PRE);  // Q prescaled
  gemm_bias<false, 1><<<gg, bb, 0, stream>>>(x, wk, bk, Kb, 1.0f);
  gemm_bias<false, 2><<<gg, bb, 0, stream>>>(x, wv, bv, Vtb, 1.0f);
  attn_kernel<<<dim3(SEQ / 64, NH), bb, 0, stream>>>(Qb, Kb, Vtb, AOb);
  gemm_bias<true, 0><<<gg, bb, 0, stream>>>(AOb, ww, bw, (float*)d_out, 1.0f);
}